// Round 1
// baseline (133.177 us; speedup 1.0000x reference)
//
#include <hip/hip_runtime.h>
#include <hip/hip_bf16.h>
#include <cstddef>

#define D_IN  4096
#define D_OUT 4096
#define BB    64
#define KSPLIT 4
#define JB    64

// ---------------------------------------------------------------------------
// Phase 2: scatter corner weights into dense AT[D_OUT][D_IN] (f32, 64 MB)
// ---------------------------------------------------------------------------
__global__ __launch_bounds__(256) void scatter_kernel(
    const float2* __restrict__ ind, const float* __restrict__ val,
    float* __restrict__ AT, int n) {
  int i = blockIdx.x * 256 + threadIdx.x;
  if (i >= n) return;
  float2 rc = ind[i];
  float v = val[i];
  float r = rc.x, c = rc.y;
  float flr = floorf(r), cer = ceilf(r);
  float flc = floorf(c), cec = ceilf(c);
  // reference weight: prod_k (1 - |corner_k - ind_k|)
  float wfr = 1.0f - (r - flr);
  float wcr = 1.0f - (cer - r);
  float wfc = 1.0f - (c - flc);
  float wcc = 1.0f - (cec - c);
  int ifr = (int)flr, icr = (int)cer;
  int ifc = (int)flc, icc = (int)cec;
  // AT[col][row] += w  (4 corners; duplicates at integer indices double-count,
  // matching the reference's itertools.product enumeration)
  atomicAdd(&AT[(size_t)ifc * D_IN + ifr], v * wfc * wfr);
  atomicAdd(&AT[(size_t)ifc * D_IN + icr], v * wfc * wcr);
  atomicAdd(&AT[(size_t)icc * D_IN + ifr], v * wcc * wfr);
  atomicAdd(&AT[(size_t)icc * D_IN + icr], v * wcc * wcr);
}

// ---------------------------------------------------------------------------
// Phase 3: out[4096,64] = AT[4096,4096] * x[4096,64], f32 vector FMA.
// Block: 256 threads, JB=64 output rows, K-split 4 (atomic f32 epilogue).
// Register tile: 4 j x 4 b per thread.
// ---------------------------------------------------------------------------
__global__ __launch_bounds__(256) void gemm_f32_kernel(
    const float* __restrict__ AT, const float* __restrict__ x,
    float* __restrict__ out) {
  // at_s padded 128->136 floats/row: jslot stride = 4 rows * 544B -> bank +8,
  // so the 4 jslot groups of a wave hit distinct banks on ds_read_b128.
  __shared__ float at_s[JB][136];
  __shared__ float xs[128 * BB];

  const int tid   = threadIdx.x;
  const int j0    = blockIdx.x * JB;
  const int kbase = blockIdx.y * (D_IN / KSPLIT);   // 1024 per split
  const int bq    = tid & 15;    // b-quad index
  const int jslot = tid >> 4;    // 0..15
  const int b0    = bq * 4;

  float4 acc[4];
#pragma unroll
  for (int jj = 0; jj < 4; jj++) acc[jj] = make_float4(0.f, 0.f, 0.f, 0.f);

  for (int kc = 0; kc < D_IN / KSPLIT; kc += 128) {
    const int k0 = kbase + kc;
    // stage x[k0..k0+128][0..64] -> xs (contiguous 32 KB)
    {
      const float4* xg = (const float4*)(x + (size_t)k0 * BB);
      float4* xs4 = (float4*)xs;
#pragma unroll
      for (int i = 0; i < 8; i++) xs4[tid + i * 256] = xg[tid + i * 256];
    }
    // stage AT[j0..j0+64][k0..k0+128] -> at_s
    {
      const int col4  = tid & 31;   // float4 within the 128-wide row chunk
      const int rbase = tid >> 5;   // 0..7
#pragma unroll
      for (int rr = 0; rr < 8; rr++) {
        int row = rbase + rr * 8;
        float4 v = *(const float4*)(AT + (size_t)(j0 + row) * D_IN + k0 + col4 * 4);
        *(float4*)&at_s[row][col4 * 4] = v;
      }
    }
    __syncthreads();

#pragma unroll 4
    for (int k4 = 0; k4 < 32; k4++) {
      float4 xv[4];
#pragma unroll
      for (int kk = 0; kk < 4; kk++)
        xv[kk] = *(const float4*)&xs[(k4 * 4 + kk) * BB + b0];
#pragma unroll
      for (int jj = 0; jj < 4; jj++) {
        float4 av = *(const float4*)&at_s[jslot * 4 + jj][k4 * 4];
#define FMA4(A, XV)                                   \
        acc[jj].x = fmaf(A, XV.x, acc[jj].x);         \
        acc[jj].y = fmaf(A, XV.y, acc[jj].y);         \
        acc[jj].z = fmaf(A, XV.z, acc[jj].z);         \
        acc[jj].w = fmaf(A, XV.w, acc[jj].w);
        FMA4(av.x, xv[0])
        FMA4(av.y, xv[1])
        FMA4(av.z, xv[2])
        FMA4(av.w, xv[3])
#undef FMA4
      }
    }
    __syncthreads();
  }

  // K-split epilogue: accumulate into out with f32 atomics
#pragma unroll
  for (int jj = 0; jj < 4; jj++) {
    int j = j0 + jslot * 4 + jj;
    float* op = out + (size_t)j * BB + b0;
    atomicAdd(op + 0, acc[jj].x);
    atomicAdd(op + 1, acc[jj].y);
    atomicAdd(op + 2, acc[jj].z);
    atomicAdd(op + 3, acc[jj].w);
  }
}

// ---------------------------------------------------------------------------
// Fallback (ws too small for 64 MB dense AT): direct atomic scatter into out.
// One wave per point; lane = b. Rows combined: 2 atomics/lane/point.
// ---------------------------------------------------------------------------
__global__ __launch_bounds__(256) void direct_kernel(
    const float2* __restrict__ ind, const float* __restrict__ val,
    const float* __restrict__ x, float* __restrict__ out, int n) {
  int p = blockIdx.x * 4 + (threadIdx.x >> 6);
  if (p >= n) return;
  int lane = threadIdx.x & 63;
  float2 rc = ind[p];
  float v = val[p];
  float flr = floorf(rc.x), cer = ceilf(rc.x);
  float flc = floorf(rc.y), cec = ceilf(rc.y);
  float wfr = 1.0f - (rc.x - flr);
  float wcr = 1.0f - (cer - rc.x);
  float wfc = 1.0f - (rc.y - flc);
  float wcc = 1.0f - (cec - rc.y);
  float xf = x[(size_t)((int)flr) * BB + lane];
  float xc = x[(size_t)((int)cer) * BB + lane];
  float inner = fmaf(wfr, xf, wcr * xc);   // handles flr==cer double-count
  atomicAdd(&out[(size_t)((int)flc) * BB + lane], v * wfc * inner);
  atomicAdd(&out[(size_t)((int)cec) * BB + lane], v * wcc * inner);
}

// ---------------------------------------------------------------------------
extern "C" void kernel_launch(void* const* d_in, const int* in_sizes, int n_in,
                              void* d_out, int out_size, void* d_ws, size_t ws_size,
                              hipStream_t stream) {
  const float2* ind = (const float2*)d_in[0];   // [N,2] f32
  const float*  val = (const float*)d_in[1];    // [N]   f32
  const float*  x   = (const float*)d_in[2];    // [D_IN*B] f32
  float* out = (float*)d_out;                   // [D_OUT*B] f32
  const int N = in_sizes[1];

  const size_t at_bytes = (size_t)D_OUT * D_IN * sizeof(float);

  if (ws_size >= at_bytes) {
    float* AT = (float*)d_ws;
    hipMemsetAsync(AT, 0, at_bytes, stream);
    hipMemsetAsync(out, 0, (size_t)out_size * sizeof(float), stream);
    scatter_kernel<<<(N + 255) / 256, 256, 0, stream>>>(ind, val, AT, N);
    dim3 grid(D_OUT / JB, KSPLIT, 1);
    gemm_f32_kernel<<<grid, 256, 0, stream>>>(AT, x, out);
  } else {
    hipMemsetAsync(out, 0, (size_t)out_size * sizeof(float), stream);
    direct_kernel<<<(N + 3) / 4, 256, 0, stream>>>(ind, val, x, out, N);
  }
}

// Round 3
// 73.561 us; speedup vs baseline: 1.8104x; 1.8104x over previous
//
#include <hip/hip_runtime.h>
#include <cstddef>
#include <cstdint>

#define D_IN  4096
#define D_OUT 4096
#define BB    64
#define PBIN  256   // slots per column bin: mean 128, sigma 11.3 -> 11-sigma headroom

// ws layout: [cnt: D_OUT u32 = 16KB][bins: D_OUT * PBIN * 16B = 16MB]
// Entry (16B as float4): .x = bits(rowf | rowc<<16), .y = wf, .z = wc, .w = 0
//   contribution to out[col,:]: wf * x[rowf,:] + wc * x[rowc,:]
//   integer row (rowf==rowc) naturally reproduces the reference double-count.

// ---------------------------------------------------------------------------
// Phase 1: bin the 2 column-corners of each point into per-column entry lists
// ---------------------------------------------------------------------------
__global__ __launch_bounds__(256) void bin_kernel(
    const float2* __restrict__ ind, const float* __restrict__ val,
    uint32_t* __restrict__ cnt, float4* __restrict__ bins, int n) {
  int i = blockIdx.x * 256 + threadIdx.x;
  if (i >= n) return;
  float2 rc = ind[i];
  float v = val[i];
  float flr = floorf(rc.x), cer = ceilf(rc.x);
  float flc = floorf(rc.y), cec = ceilf(rc.y);
  // reference weight: prod_k (1 - |corner_k - ind_k|)
  float wfr = 1.0f - (rc.x - flr);
  float wcr = 1.0f - (cer - rc.x);
  float wfc = 1.0f - (rc.y - flc);
  float wcc = 1.0f - (cec - rc.y);
  uint32_t rows = (uint32_t)(int)flr | ((uint32_t)(int)cer << 16);
  int col0 = (int)flc, col1 = (int)cec;   // col0==col1 at integer col: two
                                          // entries in the same bin = double-count, correct.
  float4 e0, e1;
  e0.x = __uint_as_float(rows); e0.y = v * wfc * wfr; e0.z = v * wfc * wcr; e0.w = 0.f;
  e1.x = __uint_as_float(rows); e1.y = v * wcc * wfr; e1.z = v * wcc * wcr; e1.w = 0.f;
  uint32_t s0 = atomicAdd(&cnt[col0], 1u);
  if (s0 < PBIN) bins[(size_t)col0 * PBIN + s0] = e0;
  uint32_t s1 = atomicAdd(&cnt[col1], 1u);
  if (s1 < PBIN) bins[(size_t)col1 * PBIN + s1] = e1;
}

// ---------------------------------------------------------------------------
// Phase 2: one wave per output column. lane = b. Gather x rows (L2-resident),
// accumulate in a register, one coalesced non-atomic store. No out memset.
// ---------------------------------------------------------------------------
__global__ __launch_bounds__(256) void accum_kernel(
    const uint32_t* __restrict__ cnt, const float4* __restrict__ bins,
    const float* __restrict__ x, float* __restrict__ out) {
  const int col = __builtin_amdgcn_readfirstlane(
      (int)(blockIdx.x * 4 + (threadIdx.x >> 6)));
  const int lane = threadIdx.x & 63;
  int n = (int)cnt[col];
  n = n < PBIN ? n : PBIN;
  const float4* __restrict__ bin = bins + (size_t)col * PBIN;

  float acc = 0.f;
  int e = 0;
  for (; e + 4 <= n; e += 4) {
    float4 q0 = bin[e + 0];
    float4 q1 = bin[e + 1];
    float4 q2 = bin[e + 2];
    float4 q3 = bin[e + 3];
    uint32_t r0 = __float_as_uint(q0.x);
    uint32_t r1 = __float_as_uint(q1.x);
    uint32_t r2 = __float_as_uint(q2.x);
    uint32_t r3 = __float_as_uint(q3.x);
    float xf0 = x[(size_t)(r0 & 0xffffu) * BB + lane];
    float xc0 = x[(size_t)(r0 >> 16) * BB + lane];
    float xf1 = x[(size_t)(r1 & 0xffffu) * BB + lane];
    float xc1 = x[(size_t)(r1 >> 16) * BB + lane];
    float xf2 = x[(size_t)(r2 & 0xffffu) * BB + lane];
    float xc2 = x[(size_t)(r2 >> 16) * BB + lane];
    float xf3 = x[(size_t)(r3 & 0xffffu) * BB + lane];
    float xc3 = x[(size_t)(r3 >> 16) * BB + lane];
    acc = fmaf(q0.y, xf0, acc); acc = fmaf(q0.z, xc0, acc);
    acc = fmaf(q1.y, xf1, acc); acc = fmaf(q1.z, xc1, acc);
    acc = fmaf(q2.y, xf2, acc); acc = fmaf(q2.z, xc2, acc);
    acc = fmaf(q3.y, xf3, acc); acc = fmaf(q3.z, xc3, acc);
  }
  for (; e < n; e++) {
    float4 q = bin[e];
    uint32_t r = __float_as_uint(q.x);
    float xf = x[(size_t)(r & 0xffffu) * BB + lane];
    float xc = x[(size_t)(r >> 16) * BB + lane];
    acc = fmaf(q.y, xf, acc);
    acc = fmaf(q.z, xc, acc);
  }
  out[(size_t)col * BB + lane] = acc;
}

// ---------------------------------------------------------------------------
// Fallback (ws too small): direct atomic scatter into out (f32).
// ---------------------------------------------------------------------------
__global__ __launch_bounds__(256) void direct_kernel(
    const float2* __restrict__ ind, const float* __restrict__ val,
    const float* __restrict__ x, float* __restrict__ out, int n) {
  int p = blockIdx.x * 4 + (threadIdx.x >> 6);
  if (p >= n) return;
  int lane = threadIdx.x & 63;
  float2 rc = ind[p];
  float v = val[p];
  float flr = floorf(rc.x), cer = ceilf(rc.x);
  float flc = floorf(rc.y), cec = ceilf(rc.y);
  float wfr = 1.0f - (rc.x - flr);
  float wcr = 1.0f - (cer - rc.x);
  float wfc = 1.0f - (rc.y - flc);
  float wcc = 1.0f - (cec - rc.y);
  float xf = x[(size_t)((int)flr) * BB + lane];
  float xc = x[(size_t)((int)cer) * BB + lane];
  float inner = fmaf(wfr, xf, wcr * xc);
  atomicAdd(&out[(size_t)((int)flc) * BB + lane], v * wfc * inner);
  atomicAdd(&out[(size_t)((int)cec) * BB + lane], v * wcc * inner);
}

// ---------------------------------------------------------------------------
extern "C" void kernel_launch(void* const* d_in, const int* in_sizes, int n_in,
                              void* d_out, int out_size, void* d_ws, size_t ws_size,
                              hipStream_t stream) {
  const float2* ind = (const float2*)d_in[0];   // [N,2] f32
  const float*  val = (const float*)d_in[1];    // [N]   f32
  const float*  x   = (const float*)d_in[2];    // [D_IN*B] f32
  float* out = (float*)d_out;                   // [D_OUT*B] f32
  const int N = in_sizes[1];

  const size_t cnt_bytes = (size_t)D_OUT * sizeof(uint32_t);          // 16 KB
  const size_t bin_bytes = (size_t)D_OUT * PBIN * sizeof(float4);     // 16 MB

  if (ws_size >= cnt_bytes + bin_bytes) {
    uint32_t* cnt = (uint32_t*)d_ws;
    float4* bins = (float4*)((char*)d_ws + cnt_bytes);
    (void)hipMemsetAsync(cnt, 0, cnt_bytes, stream);
    bin_kernel<<<(N + 255) / 256, 256, 0, stream>>>(ind, val, cnt, bins, N);
    accum_kernel<<<D_OUT / 4, 256, 0, stream>>>(cnt, bins, x, out);
  } else {
    (void)hipMemsetAsync(out, 0, (size_t)out_size * sizeof(float), stream);
    direct_kernel<<<(N + 3) / 4, 256, 0, stream>>>(ind, val, x, out, N);
  }
}

// Round 4
// 58.427 us; speedup vs baseline: 2.2794x; 1.2590x over previous
//
#include <hip/hip_runtime.h>
#include <cstddef>
#include <cstdint>

#define D_IN  4096
#define D_OUT 4096
#define BB    64
#define NSUB  8     // sub-bins per column (de-contend counter atomics 8x)
#define SLOTS 64    // slots per sub-bin: mean 16, Poisson P(>64) ~ e^-40

// ws layout: [cnt: D_OUT*NSUB u32 = 128KB][bins: D_OUT*NSUB*SLOTS*16B = 32MB]
// Entry (16B float4): .x = bits(rowf | rowc<<16), .y = wf, .z = wc, .w unused
//   contribution to out[col,:]: wf * x[rowf,:] + wc * x[rowc,:]
//   integer row (rowf==rowc) double-counts via wf+wc paths -> matches reference.

// ---------------------------------------------------------------------------
// Phase 1: bin the 2 column-corners of each point into per-(col,sub) lists.
// sub = blockIdx&7 so each counter sees only ~16 same-address atomics.
// ---------------------------------------------------------------------------
__global__ __launch_bounds__(256) void bin_kernel(
    const float2* __restrict__ ind, const float* __restrict__ val,
    uint32_t* __restrict__ cnt, float4* __restrict__ bins, int n) {
  int i = blockIdx.x * 256 + threadIdx.x;
  if (i >= n) return;
  const int sub = blockIdx.x & (NSUB - 1);
  float2 rc = ind[i];
  float v = val[i];
  float flr = floorf(rc.x), cer = ceilf(rc.x);
  float flc = floorf(rc.y), cec = ceilf(rc.y);
  // reference weight: prod_k (1 - |corner_k - ind_k|)
  float wfr = 1.0f - (rc.x - flr);
  float wcr = 1.0f - (cer - rc.x);
  float wfc = 1.0f - (rc.y - flc);
  float wcc = 1.0f - (cec - rc.y);
  uint32_t rows = (uint32_t)(int)flr | ((uint32_t)(int)cer << 16);
  int b0 = ((int)flc) * NSUB + sub;   // integer col: col0==col1 -> two entries
  int b1 = ((int)cec) * NSUB + sub;   // in the same sub-bin = double-count, correct
  float4 e0, e1;
  e0.x = __uint_as_float(rows); e0.y = v * wfc * wfr; e0.z = v * wfc * wcr; e0.w = 0.f;
  e1.x = __uint_as_float(rows); e1.y = v * wcc * wfr; e1.z = v * wcc * wcr; e1.w = 0.f;
  uint32_t s0 = atomicAdd(&cnt[b0], 1u);
  if (s0 < SLOTS) bins[(size_t)b0 * SLOTS + s0] = e0;
  uint32_t s1 = atomicAdd(&cnt[b1], 1u);
  if (s1 < SLOTS) bins[(size_t)b1 * SLOTS + s1] = e1;
}

// ---------------------------------------------------------------------------
// Phase 2: 2 waves per output column (one per 4-sub half), lane = b.
// Gather x rows (L2-resident), LDS pair-reduce, one coalesced store.
// Block = 256 threads = 4 waves = 2 columns. Grid = D_OUT/2.
// ---------------------------------------------------------------------------
__global__ __launch_bounds__(256) void accum_kernel(
    const uint32_t* __restrict__ cnt, const float4* __restrict__ bins,
    const float* __restrict__ x, float* __restrict__ out) {
  __shared__ float red[2][BB];
  const int tid   = threadIdx.x;
  const int lane  = tid & 63;
  const int wv    = tid >> 6;     // 0..3
  const int cpair = wv >> 1;      // which of the block's 2 columns
  const int half  = wv & 1;       // sub range: half*4 .. half*4+3
  const int col   = blockIdx.x * 2 + cpair;

  float acc = 0.f;
#pragma unroll
  for (int s = 0; s < NSUB / 2; ++s) {
    const int bidx = __builtin_amdgcn_readfirstlane(
        col * NSUB + half * (NSUB / 2) + s);
    int n = (int)cnt[bidx];
    n = n < SLOTS ? n : SLOTS;
    const float4* __restrict__ bin = bins + (size_t)bidx * SLOTS;
    int e = 0;
    for (; e + 4 <= n; e += 4) {
      float4 q0 = bin[e + 0];
      float4 q1 = bin[e + 1];
      float4 q2 = bin[e + 2];
      float4 q3 = bin[e + 3];
      uint32_t r0 = __float_as_uint(q0.x);
      uint32_t r1 = __float_as_uint(q1.x);
      uint32_t r2 = __float_as_uint(q2.x);
      uint32_t r3 = __float_as_uint(q3.x);
      float xf0 = x[(size_t)(r0 & 0xffffu) * BB + lane];
      float xc0 = x[(size_t)(r0 >> 16) * BB + lane];
      float xf1 = x[(size_t)(r1 & 0xffffu) * BB + lane];
      float xc1 = x[(size_t)(r1 >> 16) * BB + lane];
      float xf2 = x[(size_t)(r2 & 0xffffu) * BB + lane];
      float xc2 = x[(size_t)(r2 >> 16) * BB + lane];
      float xf3 = x[(size_t)(r3 & 0xffffu) * BB + lane];
      float xc3 = x[(size_t)(r3 >> 16) * BB + lane];
      acc = fmaf(q0.y, xf0, acc); acc = fmaf(q0.z, xc0, acc);
      acc = fmaf(q1.y, xf1, acc); acc = fmaf(q1.z, xc1, acc);
      acc = fmaf(q2.y, xf2, acc); acc = fmaf(q2.z, xc2, acc);
      acc = fmaf(q3.y, xf3, acc); acc = fmaf(q3.z, xc3, acc);
    }
    for (; e < n; e++) {
      float4 q = bin[e];
      uint32_t r = __float_as_uint(q.x);
      float xf = x[(size_t)(r & 0xffffu) * BB + lane];
      float xc = x[(size_t)(r >> 16) * BB + lane];
      acc = fmaf(q.y, xf, acc);
      acc = fmaf(q.z, xc, acc);
    }
  }

  if (half == 1) red[cpair][lane] = acc;
  __syncthreads();
  if (half == 0) out[(size_t)col * BB + lane] = acc + red[cpair][lane];
}

// ---------------------------------------------------------------------------
// Fallback (ws too small): direct atomic scatter into out (f32).
// ---------------------------------------------------------------------------
__global__ __launch_bounds__(256) void direct_kernel(
    const float2* __restrict__ ind, const float* __restrict__ val,
    const float* __restrict__ x, float* __restrict__ out, int n) {
  int p = blockIdx.x * 4 + (threadIdx.x >> 6);
  if (p >= n) return;
  int lane = threadIdx.x & 63;
  float2 rc = ind[p];
  float v = val[p];
  float flr = floorf(rc.x), cer = ceilf(rc.x);
  float flc = floorf(rc.y), cec = ceilf(rc.y);
  float wfr = 1.0f - (rc.x - flr);
  float wcr = 1.0f - (cer - rc.x);
  float wfc = 1.0f - (rc.y - flc);
  float wcc = 1.0f - (cec - rc.y);
  float xf = x[(size_t)((int)flr) * BB + lane];
  float xc = x[(size_t)((int)cer) * BB + lane];
  float inner = fmaf(wfr, xf, wcr * xc);
  atomicAdd(&out[(size_t)((int)flc) * BB + lane], v * wfc * inner);
  atomicAdd(&out[(size_t)((int)cec) * BB + lane], v * wcc * inner);
}

// ---------------------------------------------------------------------------
extern "C" void kernel_launch(void* const* d_in, const int* in_sizes, int n_in,
                              void* d_out, int out_size, void* d_ws, size_t ws_size,
                              hipStream_t stream) {
  const float2* ind = (const float2*)d_in[0];   // [N,2] f32
  const float*  val = (const float*)d_in[1];    // [N]   f32
  const float*  x   = (const float*)d_in[2];    // [D_IN*B] f32
  float* out = (float*)d_out;                   // [D_OUT*B] f32
  const int N = in_sizes[1];

  const size_t cnt_bytes = (size_t)D_OUT * NSUB * sizeof(uint32_t);        // 128 KB
  const size_t bin_bytes = (size_t)D_OUT * NSUB * SLOTS * sizeof(float4);  // 32 MB

  if (ws_size >= cnt_bytes + bin_bytes) {
    uint32_t* cnt = (uint32_t*)d_ws;
    float4* bins = (float4*)((char*)d_ws + cnt_bytes);
    (void)hipMemsetAsync(cnt, 0, cnt_bytes, stream);
    bin_kernel<<<(N + 255) / 256, 256, 0, stream>>>(ind, val, cnt, bins, N);
    accum_kernel<<<D_OUT / 2, 256, 0, stream>>>(cnt, bins, x, out);
  } else {
    (void)hipMemsetAsync(out, 0, (size_t)out_size * sizeof(float), stream);
    direct_kernel<<<(N + 3) / 4, 256, 0, stream>>>(ind, val, x, out, N);
  }
}

// Round 5
// 58.048 us; speedup vs baseline: 2.2943x; 1.0065x over previous
//
#include <hip/hip_runtime.h>
#include <cstddef>
#include <cstdint>

#define D_IN  4096
#define D_OUT 4096
#define BB    64
#define NSUB  8     // sub-bins per column (de-contend counter atomics 8x)
#define SLOTS 64    // slots per sub-bin: mean 16, Poisson P(>64) ~ e^-40

// ws layout: [cnt: D_OUT*NSUB u32 = 128KB][bins: D_OUT*NSUB*SLOTS*16B = 32MB]
// Entry (16B float4): .x = bits(rowf | rowc<<16), .y = wf, .z = wc, .w unused
//   contribution to out[col,:]: wf * x[rowf,:] + wc * x[rowc,:]
//   integer row (rowf==rowc) double-counts via wf+wc paths -> matches reference.

// ---------------------------------------------------------------------------
// Phase 0: zero the 128 KB counter array ourselves — the runtime's
// fillBufferAligned took ~39 us/replay for this (rocprof R4); this is ~1.5 us.
// ---------------------------------------------------------------------------
__global__ __launch_bounds__(256) void zero_cnt_kernel(uint32_t* __restrict__ cnt) {
  cnt[blockIdx.x * 256 + threadIdx.x] = 0u;
}

// ---------------------------------------------------------------------------
// Phase 1: bin the 2 column-corners of each point into per-(col,sub) lists.
// sub = blockIdx&7 so each counter sees only ~16 same-address atomics.
// ---------------------------------------------------------------------------
__global__ __launch_bounds__(256) void bin_kernel(
    const float2* __restrict__ ind, const float* __restrict__ val,
    uint32_t* __restrict__ cnt, float4* __restrict__ bins, int n) {
  int i = blockIdx.x * 256 + threadIdx.x;
  if (i >= n) return;
  const int sub = blockIdx.x & (NSUB - 1);
  float2 rc = ind[i];
  float v = val[i];
  float flr = floorf(rc.x), cer = ceilf(rc.x);
  float flc = floorf(rc.y), cec = ceilf(rc.y);
  // reference weight: prod_k (1 - |corner_k - ind_k|)
  float wfr = 1.0f - (rc.x - flr);
  float wcr = 1.0f - (cer - rc.x);
  float wfc = 1.0f - (rc.y - flc);
  float wcc = 1.0f - (cec - rc.y);
  uint32_t rows = (uint32_t)(int)flr | ((uint32_t)(int)cer << 16);
  int b0 = ((int)flc) * NSUB + sub;   // integer col: col0==col1 -> two entries
  int b1 = ((int)cec) * NSUB + sub;   // in the same sub-bin = double-count, correct
  float4 e0, e1;
  e0.x = __uint_as_float(rows); e0.y = v * wfc * wfr; e0.z = v * wfc * wcr; e0.w = 0.f;
  e1.x = __uint_as_float(rows); e1.y = v * wcc * wfr; e1.z = v * wcc * wcr; e1.w = 0.f;
  uint32_t s0 = atomicAdd(&cnt[b0], 1u);
  if (s0 < SLOTS) bins[(size_t)b0 * SLOTS + s0] = e0;
  uint32_t s1 = atomicAdd(&cnt[b1], 1u);
  if (s1 < SLOTS) bins[(size_t)b1 * SLOTS + s1] = e1;
}

// ---------------------------------------------------------------------------
// Phase 2: 2 waves per output column (one per 4-sub half), lane = b.
// Gather x rows (L2-resident), LDS pair-reduce, one coalesced store.
// Block = 256 threads = 4 waves = 2 columns. Grid = D_OUT/2.
// ---------------------------------------------------------------------------
__global__ __launch_bounds__(256) void accum_kernel(
    const uint32_t* __restrict__ cnt, const float4* __restrict__ bins,
    const float* __restrict__ x, float* __restrict__ out) {
  __shared__ float red[2][BB];
  const int tid   = threadIdx.x;
  const int lane  = tid & 63;
  const int wv    = tid >> 6;     // 0..3
  const int cpair = wv >> 1;      // which of the block's 2 columns
  const int half  = wv & 1;       // sub range: half*4 .. half*4+3
  const int col   = blockIdx.x * 2 + cpair;

  float acc = 0.f;
#pragma unroll
  for (int s = 0; s < NSUB / 2; ++s) {
    const int bidx = __builtin_amdgcn_readfirstlane(
        col * NSUB + half * (NSUB / 2) + s);
    int n = (int)cnt[bidx];
    n = n < SLOTS ? n : SLOTS;
    const float4* __restrict__ bin = bins + (size_t)bidx * SLOTS;
    int e = 0;
    for (; e + 4 <= n; e += 4) {
      float4 q0 = bin[e + 0];
      float4 q1 = bin[e + 1];
      float4 q2 = bin[e + 2];
      float4 q3 = bin[e + 3];
      uint32_t r0 = __float_as_uint(q0.x);
      uint32_t r1 = __float_as_uint(q1.x);
      uint32_t r2 = __float_as_uint(q2.x);
      uint32_t r3 = __float_as_uint(q3.x);
      float xf0 = x[(size_t)(r0 & 0xffffu) * BB + lane];
      float xc0 = x[(size_t)(r0 >> 16) * BB + lane];
      float xf1 = x[(size_t)(r1 & 0xffffu) * BB + lane];
      float xc1 = x[(size_t)(r1 >> 16) * BB + lane];
      float xf2 = x[(size_t)(r2 & 0xffffu) * BB + lane];
      float xc2 = x[(size_t)(r2 >> 16) * BB + lane];
      float xf3 = x[(size_t)(r3 & 0xffffu) * BB + lane];
      float xc3 = x[(size_t)(r3 >> 16) * BB + lane];
      acc = fmaf(q0.y, xf0, acc); acc = fmaf(q0.z, xc0, acc);
      acc = fmaf(q1.y, xf1, acc); acc = fmaf(q1.z, xc1, acc);
      acc = fmaf(q2.y, xf2, acc); acc = fmaf(q2.z, xc2, acc);
      acc = fmaf(q3.y, xf3, acc); acc = fmaf(q3.z, xc3, acc);
    }
    for (; e < n; e++) {
      float4 q = bin[e];
      uint32_t r = __float_as_uint(q.x);
      float xf = x[(size_t)(r & 0xffffu) * BB + lane];
      float xc = x[(size_t)(r >> 16) * BB + lane];
      acc = fmaf(q.y, xf, acc);
      acc = fmaf(q.z, xc, acc);
    }
  }

  if (half == 1) red[cpair][lane] = acc;
  __syncthreads();
  if (half == 0) out[(size_t)col * BB + lane] = acc + red[cpair][lane];
}

// ---------------------------------------------------------------------------
// Fallback (ws too small): direct atomic scatter into out (f32).
// ---------------------------------------------------------------------------
__global__ __launch_bounds__(256) void direct_kernel(
    const float2* __restrict__ ind, const float* __restrict__ val,
    const float* __restrict__ x, float* __restrict__ out, int n) {
  int p = blockIdx.x * 4 + (threadIdx.x >> 6);
  if (p >= n) return;
  int lane = threadIdx.x & 63;
  float2 rc = ind[p];
  float v = val[p];
  float flr = floorf(rc.x), cer = ceilf(rc.x);
  float flc = floorf(rc.y), cec = ceilf(rc.y);
  float wfr = 1.0f - (rc.x - flr);
  float wcr = 1.0f - (cer - rc.x);
  float wfc = 1.0f - (rc.y - flc);
  float wcc = 1.0f - (cec - rc.y);
  float xf = x[(size_t)((int)flr) * BB + lane];
  float xc = x[(size_t)((int)cer) * BB + lane];
  float inner = fmaf(wfr, xf, wcr * xc);
  atomicAdd(&out[(size_t)((int)flc) * BB + lane], v * wfc * inner);
  atomicAdd(&out[(size_t)((int)cec) * BB + lane], v * wcc * inner);
}

// ---------------------------------------------------------------------------
extern "C" void kernel_launch(void* const* d_in, const int* in_sizes, int n_in,
                              void* d_out, int out_size, void* d_ws, size_t ws_size,
                              hipStream_t stream) {
  const float2* ind = (const float2*)d_in[0];   // [N,2] f32
  const float*  val = (const float*)d_in[1];    // [N]   f32
  const float*  x   = (const float*)d_in[2];    // [D_IN*B] f32
  float* out = (float*)d_out;                   // [D_OUT*B] f32
  const int N = in_sizes[1];

  const size_t cnt_bytes = (size_t)D_OUT * NSUB * sizeof(uint32_t);        // 128 KB
  const size_t bin_bytes = (size_t)D_OUT * NSUB * SLOTS * sizeof(float4);  // 32 MB

  if (ws_size >= cnt_bytes + bin_bytes) {
    uint32_t* cnt = (uint32_t*)d_ws;
    float4* bins = (float4*)((char*)d_ws + cnt_bytes);
    zero_cnt_kernel<<<(D_OUT * NSUB) / 256, 256, 0, stream>>>(cnt);
    bin_kernel<<<(N + 255) / 256, 256, 0, stream>>>(ind, val, cnt, bins, N);
    accum_kernel<<<D_OUT / 2, 256, 0, stream>>>(cnt, bins, x, out);
  } else {
    (void)hipMemsetAsync(out, 0, (size_t)out_size * sizeof(float), stream);
    direct_kernel<<<(N + 3) / 4, 256, 0, stream>>>(ind, val, x, out, N);
  }
}

// Round 6
// 48.071 us; speedup vs baseline: 2.7704x; 1.2075x over previous
//
#include <hip/hip_runtime.h>
#include <hip/hip_fp16.h>
#include <cstddef>
#include <cstdint>

#define D_IN  4096
#define D_OUT 4096
#define BB    64
#define NSUB  8     // sub-bins per floor-col (accum parallelism)
#define SLOTS 64    // slots per sub-bin: mean 8, P(>64) ~ 0

// ws layout: [cnt: D_OUT*NSUB u32 = 128KB][bins: D_OUT*NSUB*SLOTS*16B = 32MB]
// ONE entry per point, keyed by FLOOR column (halves returning atomics vs R5):
//   .x = bits(rowf | rowc<<16)
//   .y = bits(f16(wfr) | f16(wcr)<<16)     row-corner weights
//   .z = w_this = v*wfc  (+ v*wcc if integer col)   -> applies to col flc
//   .w = w_next = v*wcc  (0 if integer col)         -> applies to col flc+1
// out[c,:] = sum_{e in bins[c]} e.z*(wfr*x[rf]+wcr*x[rc])
//          + sum_{e in bins[c-1]} e.w*(wfr*x[rf]+wcr*x[rc])
// Integer row (rowf==rowc, wfr=wcr=1) doubles the row term -> matches reference.

// ---------------------------------------------------------------------------
// Phase 0: zero the 128 KB counter array (runtime fill path is slow for this).
// ---------------------------------------------------------------------------
__global__ __launch_bounds__(256) void zero_cnt_kernel(uint32_t* __restrict__ cnt) {
  cnt[blockIdx.x * 256 + threadIdx.x] = 0u;
}

// ---------------------------------------------------------------------------
// Phase 1: one entry per point into bins[floor_col][sub].
// 262K returning atomics (was 524K) — predicted ~5 lane-ops/cy at LLC.
// ---------------------------------------------------------------------------
__global__ __launch_bounds__(256) void bin_kernel(
    const float2* __restrict__ ind, const float* __restrict__ val,
    uint32_t* __restrict__ cnt, float4* __restrict__ bins, int n) {
  int i = blockIdx.x * 256 + threadIdx.x;
  if (i >= n) return;
  const int sub = blockIdx.x & (NSUB - 1);
  float2 rc = ind[i];
  float v = val[i];
  float flr = floorf(rc.x), cer = ceilf(rc.x);
  float flc = floorf(rc.y), cec = ceilf(rc.y);
  // reference weight: prod_k (1 - |corner_k - ind_k|)
  float wfr = 1.0f - (rc.x - flr);
  float wcr = 1.0f - (cer - rc.x);
  float wfc = 1.0f - (rc.y - flc);
  float wcc = 1.0f - (cec - rc.y);
  uint32_t rows = (uint32_t)(int)flr | ((uint32_t)(int)cer << 16);
  bool cint = ((int)flc == (int)cec);          // integer col: both corners -> flc
  float w_this = cint ? v * (wfc + wcc) : v * wfc;
  float w_next = cint ? 0.f : v * wcc;
  uint32_t h2 = (uint32_t)__half_as_ushort(__float2half_rn(wfr))
              | ((uint32_t)__half_as_ushort(__float2half_rn(wcr)) << 16);
  int b = ((int)flc) * NSUB + sub;
  uint32_t s = atomicAdd(&cnt[b], 1u);
  if (s < SLOTS) {
    float4 e;
    e.x = __uint_as_float(rows);
    e.y = __uint_as_float(h2);
    e.z = w_this;
    e.w = w_next;
    bins[(size_t)b * SLOTS + s] = e;
  }
}

// ---------------------------------------------------------------------------
// Phase 2: 2 waves per output column (half = sub range), lane = b.
// Each wave scans its 4 subs of key=col (w_this) AND key=col-1 (w_next).
// Gathers of x are L2-resident; LDS pair-reduce; one coalesced store.
// ---------------------------------------------------------------------------
__device__ __forceinline__ float scan_bin(
    const float4* __restrict__ bin, int n, const float* __restrict__ x,
    int lane, bool use_next, float acc) {
  int e = 0;
  for (; e + 4 <= n; e += 4) {
    float4 q0 = bin[e + 0];
    float4 q1 = bin[e + 1];
    float4 q2 = bin[e + 2];
    float4 q3 = bin[e + 3];
#define TERM(Q)                                                          \
    {                                                                    \
      uint32_t rr = __float_as_uint(Q.x);                                \
      uint32_t hh = __float_as_uint(Q.y);                                \
      float wfr = __half2float(__ushort_as_half((ushort)(hh & 0xffffu)));\
      float wcr = __half2float(__ushort_as_half((ushort)(hh >> 16)));    \
      float xf = x[(size_t)(rr & 0xffffu) * BB + lane];                  \
      float xc = x[(size_t)(rr >> 16) * BB + lane];                      \
      float w = use_next ? Q.w : Q.z;                                    \
      acc = fmaf(w, fmaf(wfr, xf, wcr * xc), acc);                       \
    }
    TERM(q0) TERM(q1) TERM(q2) TERM(q3)
  }
  for (; e < n; e++) {
    float4 q = bin[e];
    TERM(q)
  }
#undef TERM
  return acc;
}

__global__ __launch_bounds__(256) void accum_kernel(
    const uint32_t* __restrict__ cnt, const float4* __restrict__ bins,
    const float* __restrict__ x, float* __restrict__ out) {
  __shared__ float red[2][BB];
  const int tid   = threadIdx.x;
  const int lane  = tid & 63;
  const int wv    = tid >> 6;     // 0..3
  const int cpair = wv >> 1;      // which of the block's 2 columns
  const int half  = wv & 1;       // sub range: half*4 .. half*4+3
  const int col   = blockIdx.x * 2 + cpair;

  float acc = 0.f;
#pragma unroll
  for (int s = 0; s < NSUB / 2; ++s) {
    // key = col (this-col weights)
    const int bidx = __builtin_amdgcn_readfirstlane(
        col * NSUB + half * (NSUB / 2) + s);
    int n = (int)cnt[bidx];
    n = n < SLOTS ? n : SLOTS;
    acc = scan_bin(bins + (size_t)bidx * SLOTS, n, x, lane, false, acc);
  }
  if (col > 0) {
#pragma unroll
    for (int s = 0; s < NSUB / 2; ++s) {
      // key = col-1 (next-col weights)
      const int bidx = __builtin_amdgcn_readfirstlane(
          (col - 1) * NSUB + half * (NSUB / 2) + s);
      int n = (int)cnt[bidx];
      n = n < SLOTS ? n : SLOTS;
      acc = scan_bin(bins + (size_t)bidx * SLOTS, n, x, lane, true, acc);
    }
  }

  if (half == 1) red[cpair][lane] = acc;
  __syncthreads();
  if (half == 0) out[(size_t)col * BB + lane] = acc + red[cpair][lane];
}

// ---------------------------------------------------------------------------
// Fallback (ws too small): direct atomic scatter into out (f32).
// ---------------------------------------------------------------------------
__global__ __launch_bounds__(256) void direct_kernel(
    const float2* __restrict__ ind, const float* __restrict__ val,
    const float* __restrict__ x, float* __restrict__ out, int n) {
  int p = blockIdx.x * 4 + (threadIdx.x >> 6);
  if (p >= n) return;
  int lane = threadIdx.x & 63;
  float2 rc = ind[p];
  float v = val[p];
  float flr = floorf(rc.x), cer = ceilf(rc.x);
  float flc = floorf(rc.y), cec = ceilf(rc.y);
  float wfr = 1.0f - (rc.x - flr);
  float wcr = 1.0f - (cer - rc.x);
  float wfc = 1.0f - (rc.y - flc);
  float wcc = 1.0f - (cec - rc.y);
  float xf = x[(size_t)((int)flr) * BB + lane];
  float xc = x[(size_t)((int)cer) * BB + lane];
  float inner = fmaf(wfr, xf, wcr * xc);
  atomicAdd(&out[(size_t)((int)flc) * BB + lane], v * wfc * inner);
  atomicAdd(&out[(size_t)((int)cec) * BB + lane], v * wcc * inner);
}

// ---------------------------------------------------------------------------
extern "C" void kernel_launch(void* const* d_in, const int* in_sizes, int n_in,
                              void* d_out, int out_size, void* d_ws, size_t ws_size,
                              hipStream_t stream) {
  const float2* ind = (const float2*)d_in[0];   // [N,2] f32
  const float*  val = (const float*)d_in[1];    // [N]   f32
  const float*  x   = (const float*)d_in[2];    // [D_IN*B] f32
  float* out = (float*)d_out;                   // [D_OUT*B] f32
  const int N = in_sizes[1];

  const size_t cnt_bytes = (size_t)D_OUT * NSUB * sizeof(uint32_t);        // 128 KB
  const size_t bin_bytes = (size_t)D_OUT * NSUB * SLOTS * sizeof(float4);  // 32 MB

  if (ws_size >= cnt_bytes + bin_bytes) {
    uint32_t* cnt = (uint32_t*)d_ws;
    float4* bins = (float4*)((char*)d_ws + cnt_bytes);
    zero_cnt_kernel<<<(D_OUT * NSUB) / 256, 256, 0, stream>>>(cnt);
    bin_kernel<<<(N + 255) / 256, 256, 0, stream>>>(ind, val, cnt, bins, N);
    accum_kernel<<<D_OUT / 2, 256, 0, stream>>>(cnt, bins, x, out);
  } else {
    (void)hipMemsetAsync(out, 0, (size_t)out_size * sizeof(float), stream);
    direct_kernel<<<(N + 3) / 4, 256, 0, stream>>>(ind, val, x, out, N);
  }
}

// Round 7
// 36.923 us; speedup vs baseline: 3.6068x; 1.3019x over previous
//
#include <hip/hip_runtime.h>
#include <hip/hip_fp16.h>
#include <cstddef>
#include <cstdint>

#define D_IN  4096
#define D_OUT 4096
#define BB    64
#define NSUB  8     // sub-bins per floor-col
#define SLOTS 64    // slots per sub-bin: mean 8, P(>64) ~ 0

// ws layout: [cnt: D_OUT*NSUB u32 = 128KB][bins: D_OUT*NSUB*SLOTS*8B = 16MB]
// ONE 8-byte entry per point, keyed by FLOOR column:
//   .x: rowf[0:11] | rint<<12 | f16(wfr)<<16
//   .y: f16(w_this) | f16(w_next)<<16
// where rint = (row is integer), rowc = rowf+1-rint, wcr = rint ? 1 : 1-wfr,
//   w_this = v*wfc (+ v*wcc if integer col), w_next = v*wcc (0 if integer col).
// out[c,:] += w_this*term for entries keyed c, w_next*term for entries keyed c-1,
//   term = wfr*x[rowf,:] + wcr*x[rowc,:]  (integer row -> 2*x[rowf,:], matches ref).

// ---------------------------------------------------------------------------
// Phase 0: zero cnt (128 KB) and out (1 MB) in one trivial kernel.
// ---------------------------------------------------------------------------
__global__ __launch_bounds__(256) void zero_kernel(
    uint32_t* __restrict__ cnt, float* __restrict__ out) {
  int i = blockIdx.x * 256 + threadIdx.x;
  if (i < D_OUT * NSUB) cnt[i] = 0u;
  int j = i - D_OUT * NSUB;
  if (j >= 0 && j < D_OUT * BB) out[j] = 0.f;
}

// ---------------------------------------------------------------------------
// Phase 1: one 8B entry per point into bins[floor_col][sub].
// 262K returning atomics (~10 us empirically) + 262K 8B scattered stores.
// ---------------------------------------------------------------------------
__global__ __launch_bounds__(256) void bin_kernel(
    const float2* __restrict__ ind, const float* __restrict__ val,
    uint32_t* __restrict__ cnt, uint2* __restrict__ bins, int n) {
  int i = blockIdx.x * 256 + threadIdx.x;
  if (i >= n) return;
  const int sub = blockIdx.x & (NSUB - 1);
  float2 rc = ind[i];
  float v = val[i];
  float flr = floorf(rc.x), cer = ceilf(rc.x);
  float flc = floorf(rc.y), cec = ceilf(rc.y);
  // reference weight: prod_k (1 - |corner_k - ind_k|)
  float wfr = 1.0f - (rc.x - flr);
  float wfc = 1.0f - (rc.y - flc);
  float wcc = 1.0f - (cec - rc.y);
  uint32_t rint = ((int)flr == (int)cer) ? 1u : 0u;
  bool cint = ((int)flc == (int)cec);
  float w_this = cint ? v * (wfc + wcc) : v * wfc;
  float w_next = cint ? 0.f : v * wcc;
  uint32_t ex = (uint32_t)(int)flr | (rint << 12)
              | ((uint32_t)__half_as_ushort(__float2half_rn(wfr)) << 16);
  uint32_t ey = (uint32_t)__half_as_ushort(__float2half_rn(w_this))
              | ((uint32_t)__half_as_ushort(__float2half_rn(w_next)) << 16);
  int b = ((int)flc) * NSUB + sub;
  uint32_t s = atomicAdd(&cnt[b], 1u);
  if (s < SLOTS) bins[(size_t)b * SLOTS + s] = make_uint2(ex, ey);
}

// ---------------------------------------------------------------------------
// Phase 2: 2 waves per column (4 subs each), lane = b. Each entry visited ONCE:
// gathered term feeds BOTH acc_this (col) and acc_next (col+1). Coalesced
// atomic adds into pre-zeroed out (~16K hot-line wave-ops, negligible).
// ---------------------------------------------------------------------------
__global__ __launch_bounds__(256) void accum_kernel(
    const uint32_t* __restrict__ cnt, const uint2* __restrict__ bins,
    const float* __restrict__ x, float* __restrict__ out) {
  const int tid  = threadIdx.x;
  const int lane = tid & 63;
  const int wv   = tid >> 6;      // 0..3
  const int cpair = wv >> 1;      // which of the block's 2 columns
  const int half  = wv & 1;       // sub range: half*4 .. half*4+3
  const int col   = blockIdx.x * 2 + cpair;

  float acc_t = 0.f, acc_n = 0.f;

#define PROC(Q)                                                           \
  {                                                                       \
    uint32_t ex_ = (Q).x, ey_ = (Q).y;                                    \
    int rowf = (int)(ex_ & 0xfffu);                                       \
    int rint = (int)((ex_ >> 12) & 1u);                                   \
    float wfr = __half2float(__ushort_as_half((ushort)(ex_ >> 16)));      \
    float wcr = rint ? 1.0f : 1.0f - wfr;                                 \
    int rowc = rowf + 1 - rint;                                           \
    float xf = x[(size_t)rowf * BB + lane];                               \
    float xc = x[(size_t)rowc * BB + lane];                               \
    float w_t = __half2float(__ushort_as_half((ushort)(ey_ & 0xffffu)));  \
    float w_n = __half2float(__ushort_as_half((ushort)(ey_ >> 16)));      \
    float term = fmaf(wfr, xf, wcr * xc);                                 \
    acc_t = fmaf(w_t, term, acc_t);                                       \
    acc_n = fmaf(w_n, term, acc_n);                                       \
  }

#pragma unroll
  for (int s = 0; s < NSUB / 2; ++s) {
    const int bidx = __builtin_amdgcn_readfirstlane(
        col * NSUB + half * (NSUB / 2) + s);
    int n = (int)cnt[bidx];
    n = n < SLOTS ? n : SLOTS;
    const uint2* __restrict__ bin = bins + (size_t)bidx * SLOTS;
    int e = 0;
    for (; e + 4 <= n; e += 4) {
      uint2 q0 = bin[e + 0];
      uint2 q1 = bin[e + 1];
      uint2 q2 = bin[e + 2];
      uint2 q3 = bin[e + 3];
      PROC(q0) PROC(q1) PROC(q2) PROC(q3)
    }
    for (; e < n; e++) {
      uint2 q = bin[e];
      PROC(q)
    }
  }
#undef PROC

  atomicAdd(&out[(size_t)col * BB + lane], acc_t);
  if (col + 1 < D_OUT) atomicAdd(&out[(size_t)(col + 1) * BB + lane], acc_n);
}

// ---------------------------------------------------------------------------
// Fallback (ws too small): direct atomic scatter into out (f32).
// ---------------------------------------------------------------------------
__global__ __launch_bounds__(256) void direct_kernel(
    const float2* __restrict__ ind, const float* __restrict__ val,
    const float* __restrict__ x, float* __restrict__ out, int n) {
  int p = blockIdx.x * 4 + (threadIdx.x >> 6);
  if (p >= n) return;
  int lane = threadIdx.x & 63;
  float2 rc = ind[p];
  float v = val[p];
  float flr = floorf(rc.x), cer = ceilf(rc.x);
  float flc = floorf(rc.y), cec = ceilf(rc.y);
  float wfr = 1.0f - (rc.x - flr);
  float wcr = 1.0f - (cer - rc.x);
  float wfc = 1.0f - (rc.y - flc);
  float wcc = 1.0f - (cec - rc.y);
  float xf = x[(size_t)((int)flr) * BB + lane];
  float xc = x[(size_t)((int)cer) * BB + lane];
  float inner = fmaf(wfr, xf, wcr * xc);
  atomicAdd(&out[(size_t)((int)flc) * BB + lane], v * wfc * inner);
  atomicAdd(&out[(size_t)((int)cec) * BB + lane], v * wcc * inner);
}

// ---------------------------------------------------------------------------
extern "C" void kernel_launch(void* const* d_in, const int* in_sizes, int n_in,
                              void* d_out, int out_size, void* d_ws, size_t ws_size,
                              hipStream_t stream) {
  const float2* ind = (const float2*)d_in[0];   // [N,2] f32
  const float*  val = (const float*)d_in[1];    // [N]   f32
  const float*  x   = (const float*)d_in[2];    // [D_IN*B] f32
  float* out = (float*)d_out;                   // [D_OUT*B] f32
  const int N = in_sizes[1];

  const size_t cnt_bytes = (size_t)D_OUT * NSUB * sizeof(uint32_t);       // 128 KB
  const size_t bin_bytes = (size_t)D_OUT * NSUB * SLOTS * sizeof(uint2);  // 16 MB

  if (ws_size >= cnt_bytes + bin_bytes) {
    uint32_t* cnt = (uint32_t*)d_ws;
    uint2* bins = (uint2*)((char*)d_ws + cnt_bytes);
    const int ztot = D_OUT * NSUB + D_OUT * BB;
    zero_kernel<<<(ztot + 255) / 256, 256, 0, stream>>>(cnt, out);
    bin_kernel<<<(N + 255) / 256, 256, 0, stream>>>(ind, val, cnt, bins, N);
    accum_kernel<<<D_OUT / 2, 256, 0, stream>>>(cnt, bins, x, out);
  } else {
    (void)hipMemsetAsync(out, 0, (size_t)out_size * sizeof(float), stream);
    direct_kernel<<<(N + 3) / 4, 256, 0, stream>>>(ind, val, x, out, N);
  }
}